// Round 5
// baseline (186.087 us; speedup 1.0000x reference)
//
#include <hip/hip_runtime.h>
#include <hip/hip_cooperative_groups.h>
#include <stdint.h>

namespace cg = cooperative_groups;

#define N_BOXES 6000
#define NT 94            // real tiles of 64
#define NTP 96           // padded tile count (unroll-3 pipeline)
#define NROWS (NTP * 64) // 6144 padded rows
#define CAP 16           // u16 suppression-list entries per row
#define NPAIRS (NT * (NT + 1) / 2)   // 4465 (rt<=ct)
#define NWAVES (NT * 16)             // 1504 producer waves
#define IOU_THR 0.5f
#define CONF_THR 0.6f

typedef unsigned long long u64;
typedef unsigned int u32;
typedef unsigned short u16;

// raw barrier: drain LDS only — global loads to registers may stay in flight
#define BAR() asm volatile("s_waitcnt lgkmcnt(0)\n\ts_barrier" ::: "memory")

__device__ __forceinline__ u64 rdlane64(u64 v, int l) {
    unsigned lo = (unsigned)__builtin_amdgcn_readlane((int)(unsigned)v, l);
    unsigned hi = (unsigned)__builtin_amdgcn_readlane((int)(unsigned)(v >> 32), l);
    return ((u64)hi << 32) | lo;
}

// ============================ FUSED COOPERATIVE KERNEL =====================
// 95 blocks x 1024 thr. Blocks 0..93: sort (R0 body) -> grid.sync -> mask
// producer (row-major round-robin pairs, per-pair done[rt] publish). Block 94:
// scan consumer (R0 body, frozen), gated by a wave-wide done[] poll before
// each distance-3 prefetch. Producer->consumer data goes through device-
// coherent atomics only (list entries: atomicOr of (j|0x8000) into zeroed
// words; diagw: agent atomic store; reader: relaxed agent loads) — no L2
// writeback/invalidate instructions anywhere.
__global__ void __launch_bounds__(1024) k_fused(
        const float* __restrict__ scores, const float4* __restrict__ boxes,
        int* __restrict__ sidx, float4* __restrict__ sboxes,
        u16* __restrict__ lists, int* __restrict__ cnt,
        u64* __restrict__ diagw, int* __restrict__ done,
        float* __restrict__ out) {
    __shared__ __align__(16) char shraw[52096];   // phase-overlaid LDS
    u64*    kt      = (u64*)shraw;                // sort: 6000 x 8 = 48,000 B
    int*    part    = (int*)(shraw + 48000);      // sort: 1024 x 4 =  4,096 B
    float4* rb      = (float4*)shraw;             // mask: 16 x 64 x 16 = 16,384 B
    u64*    removed = (u64*)shraw;                // scan: 96 x 8
    u64*    kwbuf   = (u64*)(shraw + 768);        // scan: 96 x 8

    const int tid  = threadIdx.x;
    const int bid  = blockIdx.x;
    const int w    = tid >> 6;
    const int lane = tid & 63;

    // ---------------- phase 1: sort + workspace init ----------------
    if (bid < NT) {
        const int gtid = bid * 1024 + tid;
        u32* lists_w = (u32*)lists;
        for (int j = gtid; j < NROWS * CAP / 2; j += NT * 1024) lists_w[j] = 0u;
        for (int j = gtid; j < NROWS; j += NT * 1024) cnt[j] = 0;
        for (int j = tid; j < N_BOXES; j += 1024) {
            unsigned inv = ~__float_as_uint(scores[j]);
            kt[j] = ((u64)inv << 32) | (unsigned)j;
        }
        __syncthreads();
        const int i = bid * 64 + lane;
        const int j0 = w * 375;                  // 16 segments of 375
        u64 mykey = (i < N_BOXES) ? kt[i] : 0ull;
        int cntr = 0;
#pragma unroll 5
        for (int jj = 0; jj < 375; ++jj)
            cntr += (kt[j0 + jj] < mykey) ? 1 : 0;
        part[tid] = cntr;
        __syncthreads();
        if (tid < 64 && i < N_BOXES) {
            int r = 0;
#pragma unroll
            for (int s = 0; s < 16; ++s) r += part[lane + 64 * s];
            sidx[r] = i;                         // keys distinct -> permutation
            sboxes[r] = boxes[i];
        }
    } else {
        if (tid < NTP) done[tid] = 0;
    }
    cg::this_grid().sync();   // orders init/sort for all blocks, flushes caches

    if (bid < NT) {
        // ---------------- phase 2: mask producer ----------------
        const int gw = bid * 16 + w;             // 0..1503
        u32* lw = (u32*)lists;
        for (int p = gw; p < NPAIRS; p += NWAVES) {
            // row-major triangular inverse: offs(r) = (189r - r^2)/2
            int rt = (int)((189.0f - sqrtf(35721.0f - 8.0f * (float)p)) * 0.5f);
            while ((189 * rt - rt * rt) / 2 > p) --rt;
            while ((189 * (rt + 1) - (rt + 1) * (rt + 1)) / 2 <= p) ++rt;
            const int ct = rt + (p - (189 * rt - rt * rt) / 2);
            const int row0 = rt * 64;
            const int rows = min(64, N_BOXES - row0);
            if (lane < rows) rb[w * 64 + lane] = sboxes[row0 + lane];  // wave-local stage
            const int j = ct * 64 + lane;
            const bool jvalid = (j < N_BOXES);
            float4 cb = make_float4(0.f, 0.f, 1.f, 1.f);
            if (jvalid) cb = sboxes[j];
            float carea = (cb.z - cb.x) * (cb.w - cb.y);
            const bool isdiag = (ct == rt);
            for (int i = 0; i < rows; ++i) {
                float4 rbx = rb[w * 64 + i];
                float rarea = (rbx.z - rbx.x) * (rbx.w - rbx.y);
                // identical f32 op order as the reference (_pairwise_iou)
                float iw = fmaxf(fminf(rbx.z, cb.z) - fmaxf(rbx.x, cb.x), 0.f);
                float ih = fmaxf(fminf(rbx.w, cb.w) - fmaxf(rbx.y, cb.y), 0.f);
                float inter = iw * ih;
                float iou = inter / ((rarea + carea) - inter);
                int row = row0 + i;
                bool pred = jvalid && (j > row) && (iou > IOU_THR);
                if (isdiag) {
                    u64 bal = __ballot(pred);
                    if (lane == (i & 63))
                        __hip_atomic_store(&diagw[row], bal, __ATOMIC_RELAXED,
                                           __HIP_MEMORY_SCOPE_AGENT);
                } else if (pred) {               // cross-tile edges only (~rare)
                    int slot = atomicAdd(&cnt[row], 1);
                    if (slot < CAP) {
                        int e = row * CAP + slot;        // u16 index
                        u32 val = ((u32)j | 0x8000u) << ((e & 1) * 16);
                        atomicOr(&lw[e >> 1], val);      // device-scope, onto zeros
                    }
                }
            }
            // publish: all this wave's stores are device-visible, then count
            asm volatile("s_waitcnt vmcnt(0)" ::: "memory");
            if (lane == 0)
                __hip_atomic_fetch_add(&done[rt], 1, __ATOMIC_RELAXED,
                                       __HIP_MEMORY_SCOPE_AGENT);
        }
        return;
    }

    // ---------------- phase 2/3: scan consumer (block 94) ----------------
#define POLL()                                                                 \
    {                                                                          \
        bool r0_ = (__hip_atomic_load(&done[lane], __ATOMIC_RELAXED,           \
                        __HIP_MEMORY_SCOPE_AGENT) == NT - lane);               \
        int t1_ = 64 + lane;                                                   \
        bool r1_ = (t1_ >= NT) || (__hip_atomic_load(&done[t1_],               \
                        __ATOMIC_RELAXED, __HIP_MEMORY_SCOPE_AGENT)            \
                        == NT - t1_);                                          \
        u64 nb0_ = ~__ballot(r0_);                                             \
        u64 nb1_ = ~__ballot(r1_);                                             \
        rdy = nb0_ ? (int)__builtin_ctzll(nb0_)                                \
                   : (nb1_ ? 64 + (int)__builtin_ctzll(nb1_) : 128);           \
    }
#define WAITR(need)                                                            \
    while (rdy < (need)) { POLL(); if (rdy < (need)) __builtin_amdgcn_s_sleep(2); }
#define ALD(p) __hip_atomic_load((u64*)(p), __ATOMIC_RELAXED, __HIP_MEMORY_SCOPE_AGENT)

    if (tid < 256) {
        const int row_l = tid >> 2;              // local row 0..63
        const int sg    = (tid & 3) * 4;         // entry-group start (4 u16)
        if (tid < NTP) removed[tid] = 0;
        int rdy = 0;
        WAITR(3);                                // tiles 0..2 produced
        u64 L0, L1, L2, D0, D1, D2;
        L0 = ALD(&lists[(0 * 64 + row_l) * CAP + sg]);
        L1 = ALD(&lists[(1 * 64 + row_l) * CAP + sg]);
        L2 = ALD(&lists[(2 * 64 + row_l) * CAP + sg]);
        D0 = ALD(&diagw[0 * 64 + lane]);
        D1 = ALD(&diagw[1 * 64 + lane]);
        D2 = ALD(&diagw[2 * 64 + lane]);
        __syncthreads();                         // barrier #1 (of 97)

#define FSTEP(T, LUSE, DUSE)                                                   \
    {                                                                          \
        const u64 nz = __ballot(DUSE != 0ull);                                 \
        const int row0 = (T) * 64;                                             \
        const int rem = N_BOXES - row0;                                        \
        const u64 valid = (rem >= 64) ? ~0ull                                  \
                        : ((rem <= 0) ? 0ull : ((1ull << rem) - 1ull));        \
        u64 c = valid & ~removed[(T)];                                         \
        u64 kw = 0;                                                            \
        while (c) {                                                            \
            u64 blockers = c & nz;                                             \
            if (!blockers) { kw |= c; break; }                                 \
            int g = (int)__builtin_ctzll(blockers);                            \
            u64 below = c & ((1ull << g) - 1ull);                              \
            kw |= below | (1ull << g);                                         \
            u64 df = rdlane64(DUSE, g);                                        \
            c &= ~(df | below | (1ull << g));                                  \
        }                                                                      \
        if (tid == 0) kwbuf[(T)] = kw;                                         \
        if (((kw >> row_l) & 1ull) && LUSE != 0ull) {                          \
            u32 e0 = (u32)(LUSE) & 0xFFFFu, e1 = (u32)(LUSE) >> 16;            \
            u32 e2 = (u32)(LUSE >> 32) & 0xFFFFu, e3 = (u32)(LUSE >> 48);      \
            if (e0 & 0x8000u) atomicOr(&removed[(e0 & 0x7FFFu) >> 6], 1ull << (e0 & 63)); \
            if (e1 & 0x8000u) atomicOr(&removed[(e1 & 0x7FFFu) >> 6], 1ull << (e1 & 63)); \
            if (e2 & 0x8000u) atomicOr(&removed[(e2 & 0x7FFFu) >> 6], 1ull << (e2 & 63)); \
            if (e3 & 0x8000u) atomicOr(&removed[(e3 & 0x7FFFu) >> 6], 1ull << (e3 & 63)); \
        }                                                                      \
        const int tn = ((T) + 3 < NTP) ? ((T) + 3) : ((T) + 3 - NTP);          \
        const int nd = (tn < NT) ? tn + 1 : 0;                                 \
        WAITR(nd);                                                             \
        LUSE = ALD(&lists[(tn * 64 + row_l) * CAP + sg]);                      \
        DUSE = ALD(&diagw[tn * 64 + lane]);                                    \
        BAR();                                                                 \
    }

        for (int t = 0; t < NTP; t += 3) {       // 96 BARs (barriers #2..#97)
            FSTEP(t,     L0, D0)
            FSTEP(t + 1, L1, D1)
            FSTEP(t + 2, L2, D2)
        }
#undef FSTEP
    } else {
        // parked waves: match the scan waves' 97 s_barrier executions
        __syncthreads();
        for (int t = 0; t < NTP; ++t) BAR();
    }

    // ---- epilogue: all 1024 threads, masked scores through permutation ----
    for (int p = tid; p < N_BOXES; p += 1024) {
        int orig = sidx[p];
        float s = scores[orig];
        bool k = (kwbuf[p >> 6] >> (p & 63)) & 1ull;
        out[orig] = (k && (s >= CONF_THR)) ? s : 0.0f;
    }
#undef POLL
#undef WAITR
#undef ALD
}

// ======================= FALLBACK: verbatim R0 3-kernel path ===============
__global__ void __launch_bounds__(1024) k_sort(const float* __restrict__ scores,
                                               const float4* __restrict__ boxes,
                                               int* __restrict__ sidx,
                                               float4* __restrict__ sboxes,
                                               u32* __restrict__ lists_w,
                                               int* __restrict__ cnt) {
    __shared__ u64 kt[N_BOXES];
    __shared__ int part[1024];
    const int tid = threadIdx.x;
    const int gtid = blockIdx.x * 1024 + tid;
    for (int j = gtid; j < NROWS * CAP / 2; j += NT * 1024) lists_w[j] = 0xFFFFFFFFu;
    for (int j = gtid; j < NROWS; j += NT * 1024) cnt[j] = 0;
    for (int j = tid; j < N_BOXES; j += 1024) {
        unsigned inv = ~__float_as_uint(scores[j]);
        kt[j] = ((u64)inv << 32) | (unsigned)j;
    }
    __syncthreads();
    const int il = tid & 63;
    const int i = blockIdx.x * 64 + il;
    const int j0 = (tid >> 6) * 375;
    u64 mykey = (i < N_BOXES) ? kt[i] : 0ull;
    int cntr = 0;
#pragma unroll 5
    for (int jj = 0; jj < 375; ++jj)
        cntr += (kt[j0 + jj] < mykey) ? 1 : 0;
    part[tid] = cntr;
    __syncthreads();
    if (tid < 64 && i < N_BOXES) {
        int r = 0;
#pragma unroll
        for (int s = 0; s < 16; ++s) r += part[il + 64 * s];
        sidx[r] = i;
        sboxes[r] = boxes[i];
    }
}

__global__ void k_mask(const float4* __restrict__ sboxes,
                       u16* __restrict__ lists, int* __restrict__ cnt,
                       u64* __restrict__ diagw) {
    int ct = blockIdx.x, rt = blockIdx.y;
    if (ct < rt) return;
    int lane = threadIdx.x;
    __shared__ float4 rb[64];
    int row0 = rt * 64;
    int rows = min(64, N_BOXES - row0);
    if (lane < rows) rb[lane] = sboxes[row0 + lane];
    __syncthreads();
    int j = ct * 64 + lane;
    bool jvalid = (j < N_BOXES);
    float4 cb = make_float4(0.f, 0.f, 1.f, 1.f);
    if (jvalid) cb = sboxes[j];
    float carea = (cb.z - cb.x) * (cb.w - cb.y);
    bool isdiag = (ct == rt);
    for (int i = 0; i < rows; ++i) {
        float4 rbx = rb[i];
        float rarea = (rbx.z - rbx.x) * (rbx.w - rbx.y);
        float iw = fmaxf(fminf(rbx.z, cb.z) - fmaxf(rbx.x, cb.x), 0.f);
        float ih = fmaxf(fminf(rbx.w, cb.w) - fmaxf(rbx.y, cb.y), 0.f);
        float inter = iw * ih;
        float iou = inter / ((rarea + carea) - inter);
        int row = row0 + i;
        bool pred = jvalid && (j > row) && (iou > IOU_THR);
        if (isdiag) {
            u64 bal = __ballot(pred);
            if (lane == (i & 63)) diagw[row] = bal;
        } else if (pred) {
            int slot = atomicAdd(&cnt[row], 1);
            if (slot < CAP) lists[row * CAP + slot] = (u16)j;
        }
    }
}

__global__ void __launch_bounds__(256) k_scan(const u16* __restrict__ lists,
                                              const u64* __restrict__ diagw,
                                              const int* __restrict__ sidx,
                                              const float* __restrict__ scores,
                                              float* __restrict__ out) {
    __shared__ u64 removed[NTP];
    __shared__ u64 kwbuf[NTP];
    const int tid   = threadIdx.x;
    const int lane  = tid & 63;
    const int row_l = tid >> 2;
    const int sg    = (tid & 3) * 4;
    if (tid < NTP) removed[tid] = 0;
    u64 L0, L1, L2, D0, D1, D2;
    L0 = *(const u64*)&lists[(0 * 64 + row_l) * CAP + sg];
    L1 = *(const u64*)&lists[(1 * 64 + row_l) * CAP + sg];
    L2 = *(const u64*)&lists[(2 * 64 + row_l) * CAP + sg];
    D0 = diagw[0 * 64 + lane];
    D1 = diagw[1 * 64 + lane];
    D2 = diagw[2 * 64 + lane];
    __syncthreads();
#define STEP(T, LUSE, DUSE)                                                    \
    {                                                                          \
        const u64 nz = __ballot(DUSE != 0ull);                                 \
        const int row0 = (T) * 64;                                             \
        const int rem = N_BOXES - row0;                                        \
        const u64 valid = (rem >= 64) ? ~0ull                                  \
                        : ((rem <= 0) ? 0ull : ((1ull << rem) - 1ull));        \
        u64 c = valid & ~removed[(T)];                                         \
        u64 kw = 0;                                                            \
        while (c) {                                                            \
            u64 blockers = c & nz;                                             \
            if (!blockers) { kw |= c; break; }                                 \
            int g = (int)__builtin_ctzll(blockers);                            \
            u64 below = c & ((1ull << g) - 1ull);                              \
            kw |= below | (1ull << g);                                         \
            u64 df = rdlane64(DUSE, g);                                        \
            c &= ~(df | below | (1ull << g));                                  \
        }                                                                      \
        if (tid == 0) kwbuf[(T)] = kw;                                         \
        if (((kw >> row_l) & 1ull) && LUSE != ~0ull) {                         \
            u16 e0 = (u16)(LUSE), e1 = (u16)(LUSE >> 16),                      \
                e2 = (u16)(LUSE >> 32), e3 = (u16)(LUSE >> 48);                \
            if (e0 != 0xFFFFu) atomicOr(&removed[e0 >> 6], 1ull << (e0 & 63)); \
            if (e1 != 0xFFFFu) atomicOr(&removed[e1 >> 6], 1ull << (e1 & 63)); \
            if (e2 != 0xFFFFu) atomicOr(&removed[e2 >> 6], 1ull << (e2 & 63)); \
            if (e3 != 0xFFFFu) atomicOr(&removed[e3 >> 6], 1ull << (e3 & 63)); \
        }                                                                      \
        const int tn = ((T) + 3 < NTP) ? ((T) + 3) : ((T) + 3 - NTP);          \
        LUSE = *(const u64*)&lists[(tn * 64 + row_l) * CAP + sg];              \
        DUSE = diagw[tn * 64 + lane];                                          \
        BAR();                                                                 \
    }
    for (int t = 0; t < NTP; t += 3) {
        STEP(t,     L0, D0)
        STEP(t + 1, L1, D1)
        STEP(t + 2, L2, D2)
    }
#undef STEP
    for (int p = tid; p < N_BOXES; p += 256) {
        int orig = sidx[p];
        float s = scores[orig];
        bool k = (kwbuf[p >> 6] >> (p & 63)) & 1ull;
        out[orig] = (k && (s >= CONF_THR)) ? s : 0.0f;
    }
}

extern "C" void kernel_launch(void* const* d_in, const int* in_sizes, int n_in,
                              void* d_out, int out_size, void* d_ws, size_t ws_size,
                              hipStream_t stream) {
    const float4* boxes  = (const float4*)d_in[0];  // [6000,4]
    const float*  scores = (const float*)d_in[1];   // [6000]
    float* out = (float*)d_out;                     // [6000]

    char* ws = (char*)d_ws;
    u16*    lists  = (u16*)(ws);                    // 196,608 B
    int*    cnt    = (int*)(ws + 196608);           //  24,576 B
    u64*    diagw  = (u64*)(ws + 221184);           //  49,152 B
    int*    sidx   = (int*)(ws + 270336);           //  24,000 B
    float4* sboxes = (float4*)(ws + 294336);        //  96,000 B
    int*    done   = (int*)(ws + 390336);           //     384 B (fused only)

    void* kargs[] = {(void*)&scores, (void*)&boxes, (void*)&sidx, (void*)&sboxes,
                     (void*)&lists, (void*)&cnt, (void*)&diagw, (void*)&done,
                     (void*)&out};
    hipError_t e = hipLaunchCooperativeKernel(k_fused, dim3(NT + 1), dim3(1024),
                                              kargs, 0u, stream);
    if (e != hipSuccess) {
        (void)hipGetLastError();   // clear; use proven 3-kernel path
        k_sort<<<dim3(NT), dim3(1024), 0, stream>>>(scores, boxes, sidx, sboxes,
                                                    (u32*)lists, cnt);
        k_mask<<<dim3(NT, NT), dim3(64), 0, stream>>>(sboxes, lists, cnt, diagw);
        k_scan<<<dim3(1), dim3(256), 0, stream>>>(lists, diagw, sidx, scores, out);
    }
}

// Round 7
// 130.130 us; speedup vs baseline: 1.4300x; 1.4300x over previous
//
#include <hip/hip_runtime.h>
#include <stdint.h>

#define N_BOXES 6000
#define NT 94            // 64-row tiles (k_mask granularity)
#define NTP 96           // padded 64-tile count (kwbuf/removed words)
#define NT2 47           // real 128-row tiles (scan granularity)
#define NTP2 48          // padded 128-tile count (unroll-3 pipeline)
#define NROWS (NTP * 64) // 6144 padded rows
#define CAP 16           // u16 suppression-list entries per row (sentinel 0xFFFF)
#define IOU_THR 0.5f
#define CONF_THR 0.6f

typedef unsigned long long u64;
typedef unsigned int u32;
typedef unsigned short u16;

// raw barrier: drain LDS only — global loads to registers may stay in flight
#define BAR() asm volatile("s_waitcnt lgkmcnt(0)\n\ts_barrier" ::: "memory")

__device__ __forceinline__ u64 rdlane64(u64 v, int l) {
    unsigned lo = (unsigned)__builtin_amdgcn_readlane((int)(unsigned)v, l);
    unsigned hi = (unsigned)__builtin_amdgcn_readlane((int)(unsigned)(v >> 32), l);
    return ((u64)hi << 32) | lo;
}

// ---- kernel 1: fused sort (R0 structure, frozen) + workspace init ---------
// scores uniform [0,1) -> raw float bits monotone. key = (~bits<<32)|index:
// ascending u64 == descending score, ties by ascending index (JAX stable argsort).
// R6 delta: also zero-inits diagw2 (12,288 u64) — each diag word has exactly
// one writer in k_mask, but odd-tile rows' word0 and pad rows are never written.
__global__ void __launch_bounds__(1024) k_sort(const float* __restrict__ scores,
                                               const float4* __restrict__ boxes,
                                               int* __restrict__ sidx,
                                               float4* __restrict__ sboxes,
                                               u32* __restrict__ lists_w,  // lists as u32
                                               int* __restrict__ cnt,
                                               u64* __restrict__ diagw2) {
    __shared__ u64 kt[N_BOXES];      // 48,000 B
    __shared__ int part[1024];
    const int tid = threadIdx.x;
    const int gtid = blockIdx.x * 1024 + tid;
    // init sparse-list sentinels + slot counters + diag words (96k threads)
    for (int j = gtid; j < NROWS * CAP / 2; j += NT * 1024) lists_w[j] = 0xFFFFFFFFu;
    for (int j = gtid; j < NROWS; j += NT * 1024) cnt[j] = 0;
    for (int j = gtid; j < NROWS * 2; j += NT * 1024) diagw2[j] = 0ull;

    for (int j = tid; j < N_BOXES; j += 1024) {
        unsigned inv = ~__float_as_uint(scores[j]);
        kt[j] = ((u64)inv << 32) | (unsigned)j;
    }
    __syncthreads();
    const int il = tid & 63;
    const int i = blockIdx.x * 64 + il;
    const int j0 = (tid >> 6) * 375;         // 16 segments of 375 (wave-uniform)
    u64 mykey = (i < N_BOXES) ? kt[i] : 0ull;
    int cntr = 0;
#pragma unroll 5
    for (int jj = 0; jj < 375; ++jj)
        cntr += (kt[j0 + jj] < mykey) ? 1 : 0;
    part[tid] = cntr;
    __syncthreads();
    if (tid < 64 && i < N_BOXES) {
        int r = 0;
#pragma unroll
        for (int s = 0; s < 16; ++s) r += part[il + 64 * s];
        sidx[r] = i;                 // keys distinct -> permutation
        sboxes[r] = boxes[i];
    }
}

// ---- kernel 2: pairwise IoU -> sparse lists + 128-bit diag words ----------
// R6: "diag" now means same 128-tile: blocks (2t,2t),(2t,2t+1),(2t+1,2t+1)
// write ballots to diagw2[row*2 + (ct&1)] (each word exactly one writer;
// pred keeps j>row so bits<=row are 0). Cross-128-tile edges -> lists, as
// before. k_scan's scatter therefore never touches the words being resolved.
__global__ void k_mask(const float4* __restrict__ sboxes,
                       u16* __restrict__ lists, int* __restrict__ cnt,
                       u64* __restrict__ diagw2) {
    int ct = blockIdx.x, rt = blockIdx.y;
    if (ct < rt) return;
    int lane = threadIdx.x;
    __shared__ float4 rb[64];
    int row0 = rt * 64;
    int rows = min(64, N_BOXES - row0);
    if (lane < rows) rb[lane] = sboxes[row0 + lane];
    __syncthreads();
    int j = ct * 64 + lane;
    bool jvalid = (j < N_BOXES);
    float4 cb = make_float4(0.f, 0.f, 1.f, 1.f);
    if (jvalid) cb = sboxes[j];
    float carea = (cb.z - cb.x) * (cb.w - cb.y);
    const bool indiag = ((ct >> 1) == (rt >> 1));
    const int wi = ct & 1;
    for (int i = 0; i < rows; ++i) {
        float4 rbx = rb[i];
        float rarea = (rbx.z - rbx.x) * (rbx.w - rbx.y);
        // identical f32 op order as the reference (_pairwise_iou)
        float iw = fmaxf(fminf(rbx.z, cb.z) - fmaxf(rbx.x, cb.x), 0.f);
        float ih = fmaxf(fminf(rbx.w, cb.w) - fmaxf(rbx.y, cb.y), 0.f);
        float inter = iw * ih;
        float iou = inter / ((rarea + carea) - inter);
        int row = row0 + i;
        bool pred = jvalid && (j > row) && (iou > IOU_THR);
        if (indiag) {
            u64 bal = __ballot(pred);
            if (lane == (i & 63)) diagw2[row * 2 + wi] = bal;
        } else if (pred) {           // cross-128-tile edges only (~rare)
            int slot = atomicAdd(&cnt[row], 1);
            if (slot < CAP) lists[row * CAP + slot] = (u16)j;
        }
    }
}

// ---- kernel 3: greedy scan — 128-row tiles, 48 serial steps ---------------
// R6: same 4-wave lockstep / distance-3 prefetch / 1 BAR per step structure
// (frozen since R0; micro-edits R1/R3 both regressed), but each step resolves
// 128 ranks: lane owns rowA=lane (diag words A0,A1) and rowB=64+lane (B1;
// B0==0 since suppression only targets higher ranks). Greedy: word0 to
// exhaustion, then word1. nz0 tests (A0|A1) so any word0 keeper with word1
// targets is a blocker -> its A1 is applied; word1 rows never suppress word0.
// Keep-set provably identical to the reference serial NMS. Per-step resolve
// work ~= the two 64-tiles it replaces; fixed costs (BAR, removed-read,
// kwbuf-write, prefetch issue) are paid 48x instead of 96x.
// 256 thr: scatter ownership row_l=tid>>1 (2 thr/row, 8 u16 each); resolve
// redundant in all 4 waves via lane-indexed diag regs.
__global__ void __launch_bounds__(256) k_scan(const u16* __restrict__ lists,
                                              const u64* __restrict__ diagw2,
                                              const int* __restrict__ sidx,
                                              const float* __restrict__ scores,
                                              float* __restrict__ out) {
    __shared__ u64 removed[NTP];     // 64-rank granularity (96 words)
    __shared__ u64 kwbuf[NTP];
    const int tid   = threadIdx.x;
    const int lane  = tid & 63;
    const int row_l = tid >> 1;              // local row 0..127 (scatter)
    const int sg    = (tid & 1) * 8;         // entry-group start (8 u16 = 16 B)
    if (tid < NTP) removed[tid] = 0;

    uint4 LA0, LA1, LA2;                     // list rows (8 entries each)
    ulonglong2 DAa, DAb, DAc;                // rowA diag {word0, word1}
    u64 DBa, DBb, DBc;                       // rowB diag word1
    LA0 = *(const uint4*)&lists[(0 * 128 + row_l) * CAP + sg];
    LA1 = *(const uint4*)&lists[(1 * 128 + row_l) * CAP + sg];
    LA2 = *(const uint4*)&lists[(2 * 128 + row_l) * CAP + sg];
    DAa = *(const ulonglong2*)&diagw2[(0 * 128 + lane) * 2];
    DAb = *(const ulonglong2*)&diagw2[(1 * 128 + lane) * 2];
    DAc = *(const ulonglong2*)&diagw2[(2 * 128 + lane) * 2];
    DBa = diagw2[(0 * 128 + 64 + lane) * 2 + 1];
    DBb = diagw2[(1 * 128 + 64 + lane) * 2 + 1];
    DBc = diagw2[(2 * 128 + 64 + lane) * 2 + 1];
    __syncthreads();   // full barrier once (covers removed[] init)

#define SCAT(w)                                                                \
    {   u32 e0 = (w) & 0xFFFFu, e1 = (w) >> 16;                                \
        if (e0 != 0xFFFFu) atomicOr(&removed[e0 >> 6], 1ull << (e0 & 63));     \
        if (e1 != 0xFFFFu) atomicOr(&removed[e1 >> 6], 1ull << (e1 & 63)); }

#define STEP(T, LA, DA, DB)                                                    \
    {                                                                          \
        const u64 A0 = DA.x, A1 = DA.y;                                        \
        const u64 nz0 = __ballot((A0 | A1) != 0ull);                           \
        const u64 nz1 = __ballot(DB != 0ull);                                  \
        const int rem0 = N_BOXES - (T) * 128;                                  \
        const int rem1 = rem0 - 64;                                            \
        const u64 valid0 = (rem0 >= 64) ? ~0ull                                \
                         : ((rem0 <= 0) ? 0ull : ((1ull << rem0) - 1ull));     \
        const u64 valid1 = (rem1 >= 64) ? ~0ull                                \
                         : ((rem1 <= 0) ? 0ull : ((1ull << rem1) - 1ull));     \
        u64 c0 = valid0 & ~removed[2 * (T)];                                   \
        u64 c1 = valid1 & ~removed[2 * (T) + 1];                               \
        u64 kw0 = 0, kw1 = 0;                                                  \
        while (c0 | c1) {                                                      \
            u64 b0 = c0 & nz0;                                                 \
            if (b0) {                                                          \
                int g = (int)__builtin_ctzll(b0);                              \
                u64 below = c0 & ((1ull << g) - 1ull);  /* zero-diag: kept */  \
                kw0 |= below | (1ull << g);                                    \
                u64 d0 = rdlane64(A0, g);               /* bits > g only */    \
                u64 d1 = rdlane64(A1, g);                                      \
                c0 &= ~(d0 | below | (1ull << g));                             \
                c1 &= ~d1;                                                     \
            } else {                                                           \
                kw0 |= c0; c0 = 0;     /* rest of word0: non-suppressors */    \
                u64 b1 = c1 & nz1;                                             \
                if (!b1) { kw1 |= c1; break; }          /* bulk-keep rest */   \
                int g = (int)__builtin_ctzll(b1);                              \
                u64 below = c1 & ((1ull << g) - 1ull);                         \
                kw1 |= below | (1ull << g);                                    \
                u64 d1 = rdlane64(DB, g);               /* bits > g only */    \
                c1 &= ~(d1 | below | (1ull << g));                             \
            }                                                                  \
        }                                                                      \
        if (tid == 0) { kwbuf[2 * (T)] = kw0; kwbuf[2 * (T) + 1] = kw1; }      \
        const u64 kws = (row_l < 64) ? kw0 : kw1;                              \
        if (((kws >> (row_l & 63)) & 1ull) && ((LA.x & 0xFFFFu) != 0xFFFFu)) { \
            SCAT(LA.x) SCAT(LA.y) SCAT(LA.z) SCAT(LA.w)                        \
        }                                                                      \
        const int tn = ((T) + 3 < NTP2) ? ((T) + 3) : ((T) + 3 - NTP2);        \
        LA = *(const uint4*)&lists[(tn * 128 + row_l) * CAP + sg];             \
        DA = *(const ulonglong2*)&diagw2[(tn * 128 + lane) * 2];               \
        DB = diagw2[(tn * 128 + 64 + lane) * 2 + 1];                           \
        BAR();                                                                 \
    }

    for (int t = 0; t < NTP2; t += 3) {      // NTP2 = 48 = 16 x 3
        STEP(t,     LA0, DAa, DBa)
        STEP(t + 1, LA1, DAb, DBb)
        STEP(t + 2, LA2, DAc, DBc)
    }
#undef STEP
#undef SCAT

    // ---- epilogue: masked scores through the sort permutation ----
    for (int p = tid; p < N_BOXES; p += 256) {
        int orig = sidx[p];
        float s = scores[orig];
        bool k = (kwbuf[p >> 6] >> (p & 63)) & 1ull;
        out[orig] = (k && (s >= CONF_THR)) ? s : 0.0f;  // writes ALL outputs
    }
}

extern "C" void kernel_launch(void* const* d_in, const int* in_sizes, int n_in,
                              void* d_out, int out_size, void* d_ws, size_t ws_size,
                              hipStream_t stream) {
    const float* boxes  = (const float*)d_in[0];    // [6000,4]
    const float* scores = (const float*)d_in[1];    // [6000]
    float* out = (float*)d_out;                     // [6000]

    // workspace layout
    char* ws = (char*)d_ws;
    u16*    lists  = (u16*)(ws);                    // 6144*16*2 = 196,608 B
    int*    cnt    = (int*)(ws + 196608);           // 6144*4    =  24,576 B
    u64*    diagw2 = (u64*)(ws + 221184);           // 6144*2*8  =  98,304 B
    int*    sidx   = (int*)(ws + 319488);           // 24,000 B
    float4* sboxes = (float4*)(ws + 343488);        // 96,000 B (16B aligned)

    k_sort<<<dim3(NT), dim3(1024), 0, stream>>>(scores, (const float4*)boxes, sidx,
                                                sboxes, (u32*)lists, cnt, diagw2);
    k_mask<<<dim3(NT, NT), dim3(64), 0, stream>>>((const float4*)sboxes, lists, cnt,
                                                  diagw2);
    k_scan<<<dim3(1), dim3(256), 0, stream>>>(lists, diagw2, sidx, scores, out);
}

// Round 8
// 128.076 us; speedup vs baseline: 1.4529x; 1.0160x over previous
//
#include <hip/hip_runtime.h>
#include <stdint.h>

#define N_BOXES 6000
#define NT 94            // 64-row tiles (k_mask granularity)
#define NTP 96           // padded 64-tile count (kwbuf/removed words)
#define NT2 47           // real 128-row tiles (scan granularity)
#define NTP2 48          // padded 128-tile count (unroll-3 pipeline)
#define NROWS (NTP * 64) // 6144 padded rows
#define CAP 16           // u16 suppression-list entries per row (sentinel 0xFFFF)
#define IOU_THR 0.5f
#define CONF_THR 0.6f

typedef unsigned long long u64;
typedef unsigned int u32;
typedef unsigned short u16;

// raw barrier: drain LDS only — global loads to registers may stay in flight
#define BAR() asm volatile("s_waitcnt lgkmcnt(0)\n\ts_barrier" ::: "memory")

__device__ __forceinline__ u64 rdlane64(u64 v, int l) {
    unsigned lo = (unsigned)__builtin_amdgcn_readlane((int)(unsigned)v, l);
    unsigned hi = (unsigned)__builtin_amdgcn_readlane((int)(unsigned)(v >> 32), l);
    return ((u64)hi << 32) | lo;
}

// ---- kernel 1: fused sort (R0 structure, frozen) + workspace init ---------
// scores uniform [0,1) -> raw float bits monotone. key = (~bits<<32)|index:
// ascending u64 == descending score, ties by ascending index (JAX stable argsort).
__global__ void __launch_bounds__(1024) k_sort(const float* __restrict__ scores,
                                               const float4* __restrict__ boxes,
                                               int* __restrict__ sidx,
                                               float4* __restrict__ sboxes,
                                               u32* __restrict__ lists_w,  // lists as u32
                                               int* __restrict__ cnt,
                                               u64* __restrict__ diagw2) {
    __shared__ u64 kt[N_BOXES];      // 48,000 B
    __shared__ int part[1024];
    const int tid = threadIdx.x;
    const int gtid = blockIdx.x * 1024 + tid;
    // init sparse-list sentinels + slot counters + diag words (96k threads)
    for (int j = gtid; j < NROWS * CAP / 2; j += NT * 1024) lists_w[j] = 0xFFFFFFFFu;
    for (int j = gtid; j < NROWS; j += NT * 1024) cnt[j] = 0;
    for (int j = gtid; j < NROWS * 2; j += NT * 1024) diagw2[j] = 0ull;

    for (int j = tid; j < N_BOXES; j += 1024) {
        unsigned inv = ~__float_as_uint(scores[j]);
        kt[j] = ((u64)inv << 32) | (unsigned)j;
    }
    __syncthreads();
    const int il = tid & 63;
    const int i = blockIdx.x * 64 + il;
    const int j0 = (tid >> 6) * 375;         // 16 segments of 375 (wave-uniform)
    u64 mykey = (i < N_BOXES) ? kt[i] : 0ull;
    int cntr = 0;
#pragma unroll 5
    for (int jj = 0; jj < 375; ++jj)
        cntr += (kt[j0 + jj] < mykey) ? 1 : 0;
    part[tid] = cntr;
    __syncthreads();
    if (tid < 64 && i < N_BOXES) {
        int r = 0;
#pragma unroll
        for (int s = 0; s < 16; ++s) r += part[il + 64 * s];
        sidx[r] = i;                 // keys distinct -> permutation
        sboxes[r] = boxes[i];
    }
}

// ---- kernel 2: pairwise IoU -> sparse lists + 128-bit diag words ----------
// "diag" = same 128-tile: blocks (2t,2t),(2t,2t+1),(2t+1,2t+1) write ballots
// to diagw2[row*2 + (ct&1)] (each word exactly one writer; pred keeps j>row
// so bits<=row are 0). Cross-128-tile edges -> lists.
__global__ void k_mask(const float4* __restrict__ sboxes,
                       u16* __restrict__ lists, int* __restrict__ cnt,
                       u64* __restrict__ diagw2) {
    int ct = blockIdx.x, rt = blockIdx.y;
    if (ct < rt) return;
    int lane = threadIdx.x;
    __shared__ float4 rb[64];
    int row0 = rt * 64;
    int rows = min(64, N_BOXES - row0);
    if (lane < rows) rb[lane] = sboxes[row0 + lane];
    __syncthreads();
    int j = ct * 64 + lane;
    bool jvalid = (j < N_BOXES);
    float4 cb = make_float4(0.f, 0.f, 1.f, 1.f);
    if (jvalid) cb = sboxes[j];
    float carea = (cb.z - cb.x) * (cb.w - cb.y);
    const bool indiag = ((ct >> 1) == (rt >> 1));
    const int wi = ct & 1;
    for (int i = 0; i < rows; ++i) {
        float4 rbx = rb[i];
        float rarea = (rbx.z - rbx.x) * (rbx.w - rbx.y);
        // identical f32 op order as the reference (_pairwise_iou)
        float iw = fmaxf(fminf(rbx.z, cb.z) - fmaxf(rbx.x, cb.x), 0.f);
        float ih = fmaxf(fminf(rbx.w, cb.w) - fmaxf(rbx.y, cb.y), 0.f);
        float inter = iw * ih;
        float iou = inter / ((rarea + carea) - inter);
        int row = row0 + i;
        bool pred = jvalid && (j > row) && (iou > IOU_THR);
        if (indiag) {
            u64 bal = __ballot(pred);
            if (lane == (i & 63)) diagw2[row * 2 + wi] = bal;
        } else if (pred) {           // cross-128-tile edges only (~rare)
            int slot = atomicAdd(&cnt[row], 1);
            if (slot < CAP) lists[row * CAP + slot] = (u16)j;
        }
    }
}

// ---- kernel 3: greedy scan — 128-row tiles, 2-WIDE SPECULATIVE resolve ----
// R7 decomposition: per-step fixed cost ~40ns (48F=1.9us); the scan is ~92%
// resolve-loop — a serial chain of (ctz -> readlane x4 -> mask-update) per
// kept-box-with-in-tile-targets. R8: process TWO blockers per trip. g1,g2 =
// two lowest blockers of the current word; all their readlanes are mutually
// independent (issue together, latencies overlap). Sequential equivalence:
// after applying D[g1], the next blocker is exactly g2 iff g2 NOT in D0[g1]
// (no b0-bits lie between g1 and g2); then below2 = (c0 & ~(D0[g1]|below1|
// bit g1)) & (bit(g2)-1) matches the sequential second iteration. On
// collision (g2 in D0[g1]) discard g2's masks and do the 1-wide update.
// All values wave-uniform -> branches non-divergent.
__global__ void __launch_bounds__(256) k_scan(const u16* __restrict__ lists,
                                              const u64* __restrict__ diagw2,
                                              const int* __restrict__ sidx,
                                              const float* __restrict__ scores,
                                              float* __restrict__ out) {
    __shared__ u64 removed[NTP];     // 64-rank granularity (96 words)
    __shared__ u64 kwbuf[NTP];
    const int tid   = threadIdx.x;
    const int lane  = tid & 63;
    const int row_l = tid >> 1;              // local row 0..127 (scatter)
    const int sg    = (tid & 1) * 8;         // entry-group start (8 u16 = 16 B)
    if (tid < NTP) removed[tid] = 0;

    uint4 LA0, LA1, LA2;                     // list rows (8 entries each)
    ulonglong2 DAa, DAb, DAc;                // rowA diag {word0, word1}
    u64 DBa, DBb, DBc;                       // rowB diag word1
    LA0 = *(const uint4*)&lists[(0 * 128 + row_l) * CAP + sg];
    LA1 = *(const uint4*)&lists[(1 * 128 + row_l) * CAP + sg];
    LA2 = *(const uint4*)&lists[(2 * 128 + row_l) * CAP + sg];
    DAa = *(const ulonglong2*)&diagw2[(0 * 128 + lane) * 2];
    DAb = *(const ulonglong2*)&diagw2[(1 * 128 + lane) * 2];
    DAc = *(const ulonglong2*)&diagw2[(2 * 128 + lane) * 2];
    DBa = diagw2[(0 * 128 + 64 + lane) * 2 + 1];
    DBb = diagw2[(1 * 128 + 64 + lane) * 2 + 1];
    DBc = diagw2[(2 * 128 + 64 + lane) * 2 + 1];
    __syncthreads();   // full barrier once (covers removed[] init)

#define SCAT(w)                                                                \
    {   u32 e0 = (w) & 0xFFFFu, e1 = (w) >> 16;                                \
        if (e0 != 0xFFFFu) atomicOr(&removed[e0 >> 6], 1ull << (e0 & 63));     \
        if (e1 != 0xFFFFu) atomicOr(&removed[e1 >> 6], 1ull << (e1 & 63)); }

#define STEP(T, LA, DA, DB)                                                    \
    {                                                                          \
        const u64 A0 = DA.x, A1 = DA.y;                                        \
        const u64 nz0 = __ballot((A0 | A1) != 0ull);                           \
        const u64 nz1 = __ballot(DB != 0ull);                                  \
        const int rem0 = N_BOXES - (T) * 128;                                  \
        const int rem1 = rem0 - 64;                                            \
        const u64 valid0 = (rem0 >= 64) ? ~0ull                                \
                         : ((rem0 <= 0) ? 0ull : ((1ull << rem0) - 1ull));     \
        const u64 valid1 = (rem1 >= 64) ? ~0ull                                \
                         : ((rem1 <= 0) ? 0ull : ((1ull << rem1) - 1ull));     \
        u64 c0 = valid0 & ~removed[2 * (T)];                                   \
        u64 c1 = valid1 & ~removed[2 * (T) + 1];                               \
        u64 kw0 = 0, kw1 = 0;                                                  \
        for (;;) {                           /* word0 phase, 2-wide */         \
            u64 b0 = c0 & nz0;                                                 \
            if (!b0) break;                                                    \
            int g1 = (int)__builtin_ctzll(b0);                                 \
            u64 rest = b0 & (b0 - 1);                                          \
            u64 d0a = rdlane64(A0, g1), d1a = rdlane64(A1, g1);                \
            u64 below1 = c0 & ((1ull << g1) - 1ull);  /* zero-diag: kept */    \
            kw0 |= below1 | (1ull << g1);                                      \
            if (rest) {                                                        \
                int g2 = (int)__builtin_ctzll(rest);                           \
                u64 d0b = rdlane64(A0, g2), d1b = rdlane64(A1, g2);            \
                if (!((d0a >> g2) & 1ull)) {          /* g2 survives g1 */     \
                    u64 rm1 = d0a | below1 | (1ull << g1);                     \
                    u64 below2 = (c0 & ~rm1) & ((1ull << g2) - 1ull);          \
                    kw0 |= below2 | (1ull << g2);                              \
                    c0 &= ~(rm1 | d0b | below2 | (1ull << g2));                \
                    c1 &= ~(d1a | d1b);                                        \
                    continue;                                                  \
                }                                                              \
            }                                                                  \
            c0 &= ~(d0a | below1 | (1ull << g1));                              \
            c1 &= ~d1a;                                                        \
        }                                                                      \
        kw0 |= c0;                           /* leftovers: non-blockers */     \
        for (;;) {                           /* word1 phase, 2-wide */         \
            u64 b1 = c1 & nz1;                                                 \
            if (!b1) { kw1 |= c1; break; }   /* bulk-keep rest */              \
            int g1 = (int)__builtin_ctzll(b1);                                 \
            u64 rest = b1 & (b1 - 1);                                          \
            u64 d1a = rdlane64(DB, g1);                                        \
            u64 below1 = c1 & ((1ull << g1) - 1ull);                           \
            kw1 |= below1 | (1ull << g1);                                      \
            if (rest) {                                                        \
                int g2 = (int)__builtin_ctzll(rest);                           \
                u64 d1b = rdlane64(DB, g2);                                    \
                if (!((d1a >> g2) & 1ull)) {                                   \
                    u64 rm1 = d1a | below1 | (1ull << g1);                     \
                    u64 below2 = (c1 & ~rm1) & ((1ull << g2) - 1ull);          \
                    kw1 |= below2 | (1ull << g2);                              \
                    c1 &= ~(rm1 | d1b | below2 | (1ull << g2));                \
                    continue;                                                  \
                }                                                              \
            }                                                                  \
            c1 &= ~(d1a | below1 | (1ull << g1));                              \
        }                                                                      \
        if (tid == 0) { kwbuf[2 * (T)] = kw0; kwbuf[2 * (T) + 1] = kw1; }      \
        const u64 kws = (row_l < 64) ? kw0 : kw1;                              \
        if (((kws >> (row_l & 63)) & 1ull) && ((LA.x & 0xFFFFu) != 0xFFFFu)) { \
            SCAT(LA.x) SCAT(LA.y) SCAT(LA.z) SCAT(LA.w)                        \
        }                                                                      \
        const int tn = ((T) + 3 < NTP2) ? ((T) + 3) : ((T) + 3 - NTP2);        \
        LA = *(const uint4*)&lists[(tn * 128 + row_l) * CAP + sg];             \
        DA = *(const ulonglong2*)&diagw2[(tn * 128 + lane) * 2];               \
        DB = diagw2[(tn * 128 + 64 + lane) * 2 + 1];                           \
        BAR();                                                                 \
    }

    for (int t = 0; t < NTP2; t += 3) {      // NTP2 = 48 = 16 x 3
        STEP(t,     LA0, DAa, DBa)
        STEP(t + 1, LA1, DAb, DBb)
        STEP(t + 2, LA2, DAc, DBc)
    }
#undef STEP
#undef SCAT

    // ---- epilogue: masked scores through the sort permutation ----
    for (int p = tid; p < N_BOXES; p += 256) {
        int orig = sidx[p];
        float s = scores[orig];
        bool k = (kwbuf[p >> 6] >> (p & 63)) & 1ull;
        out[orig] = (k && (s >= CONF_THR)) ? s : 0.0f;  // writes ALL outputs
    }
}

extern "C" void kernel_launch(void* const* d_in, const int* in_sizes, int n_in,
                              void* d_out, int out_size, void* d_ws, size_t ws_size,
                              hipStream_t stream) {
    const float* boxes  = (const float*)d_in[0];    // [6000,4]
    const float* scores = (const float*)d_in[1];    // [6000]
    float* out = (float*)d_out;                     // [6000]

    // workspace layout
    char* ws = (char*)d_ws;
    u16*    lists  = (u16*)(ws);                    // 6144*16*2 = 196,608 B
    int*    cnt    = (int*)(ws + 196608);           // 6144*4    =  24,576 B
    u64*    diagw2 = (u64*)(ws + 221184);           // 6144*2*8  =  98,304 B
    int*    sidx   = (int*)(ws + 319488);           // 24,000 B
    float4* sboxes = (float4*)(ws + 343488);        // 96,000 B (16B aligned)

    k_sort<<<dim3(NT), dim3(1024), 0, stream>>>(scores, (const float4*)boxes, sidx,
                                                sboxes, (u32*)lists, cnt, diagw2);
    k_mask<<<dim3(NT, NT), dim3(64), 0, stream>>>((const float4*)sboxes, lists, cnt,
                                                  diagw2);
    k_scan<<<dim3(1), dim3(256), 0, stream>>>(lists, diagw2, sidx, scores, out);
}